// Round 7
// baseline (147.609 us; speedup 1.0000x reference)
//
#include <hip/hip_runtime.h>

#define NWT   62500          // 1,000,000 rows / 16 rows per wave-tile
#define GRID  512
#define WPB   6              // waves per block (384 threads)
#define TOTW  (GRID * WPB)   // 3072 waves

typedef __attribute__((ext_vector_type(8))) short bf16x8;
typedef __attribute__((ext_vector_type(4))) float f32x4;

static __device__ __forceinline__ short f2b(float f) {
    __bf16 h = (__bf16)f;                 // hardware RNE
    return __builtin_bit_cast(short, h);
}
static __device__ __forceinline__ float b2f(short s) {
    unsigned u = ((unsigned)(unsigned short)s) << 16;
    return __builtin_bit_cast(float, u);
}
static __device__ __forceinline__ unsigned pack2(float lo, float hi) {
    return ((unsigned)(unsigned short)f2b(lo)) |
           (((unsigned)(unsigned short)f2b(hi)) << 16);
}
static __device__ __forceinline__ float tanh_fast(float x) {
    float e = __expf(2.0f * x);
    return 1.0f - 2.0f * __builtin_amdgcn_rcpf(e + 1.0f);
}

// acc = Xaug @ Baug(LDS) + A @ W(LDS)   (12 x mfma_f32_16x16x32_bf16)
static __device__ __forceinline__ void gate_mm(const char* lWg, const char* lBg,
                                               const int (&baOff)[4], const int (&wOff)[2][4],
                                               bf16x8 aX, bf16x8 a0, bf16x8 a1,
                                               f32x4 (&acc)[4])
{
    #pragma unroll
    for (int nt = 0; nt < 4; ++nt) {
        bf16x8 bx = *(const bf16x8*)(lBg + baOff[nt]);
        f32x4 z4 = {0.f, 0.f, 0.f, 0.f};
        acc[nt] = __builtin_amdgcn_mfma_f32_16x16x32_bf16(aX, bx, z4, 0, 0, 0);
    }
    #pragma unroll
    for (int ks = 0; ks < 2; ++ks) {
        bf16x8 a = ks ? a1 : a0;
        #pragma unroll
        for (int nt = 0; nt < 4; ++nt) {
            bf16x8 bw = *(const bf16x8*)(lWg + wOff[ks][nt]);
            acc[nt] = __builtin_amdgcn_mfma_f32_16x16x32_bf16(a, bw, acc[nt], 0, 0, 0);
        }
    }
}

__global__ __launch_bounds__(384, 3)
void dgm_lstm_kernel(const float* __restrict__ S, const float* __restrict__ X,
                     const float* __restrict__ U0, const float* __restrict__ U1,
                     const float* __restrict__ U2, const float* __restrict__ U3,
                     const float* __restrict__ W0, const float* __restrict__ W1,
                     const float* __restrict__ W2, const float* __restrict__ W3,
                     const float* __restrict__ b0, const float* __restrict__ b1,
                     const float* __restrict__ b2, const float* __restrict__ b3,
                     float* __restrict__ Out)
{
    // gate order: 0=z, 1=g, 2=r, 3=h
    __shared__ __align__(16) unsigned short lWT[4][64][64]; // 32 KB: W^T bf16, XOR-swizzled
    __shared__ __align__(16) unsigned short lBa[4][65][8];  // 4.1 KB: [U0,U1,U2,b,0..]; row 64 = zeros
    __shared__ __align__(16) float          lS[WPB][16][68];// 25.5 KB: S tile f32, wave-private, pad->68
    __shared__ __align__(16) unsigned short lR[WPB][16][64];// 12 KB: R bf16, wave-private

    const int tid = threadIdx.x;

    // ---- one-time staging: W^T bf16 swizzled; Baug table ----
    {
        const float* Ws[4] = {W0, W1, W2, W3};
        #pragma unroll
        for (int g = 0; g < 4; ++g) {
            #pragma unroll
            for (int it = 0; it < 6; ++it) {
                int p = it * 384 + tid;             // 0..2303, use 0..2047
                if (p < 2048) {
                    int n  = p & 63;
                    int k2 = (p >> 6) << 1;
                    float w0 = Ws[g][k2 * 64 + n];
                    float w1 = Ws[g][k2 * 64 + 64 + n];
                    int byt = ((n << 7) + (k2 << 1)) ^ ((n & 7) << 4);
                    *(unsigned*)((char*)(&lWT[0][0][0]) + (g << 13) + byt) = pack2(w0, w1);
                }
            }
        }
        if (tid < 256) {
            const float* Us[4] = {U0, U1, U2, U3};
            const float* bs[4] = {b0, b1, b2, b3};
            int g = tid >> 6, n = tid & 63;
            bf16x8 f = {};
            f[0] = f2b(Us[g][n]);       f[1] = f2b(Us[g][64 + n]);
            f[2] = f2b(Us[g][128 + n]); f[3] = f2b(bs[g][n]);
            *(bf16x8*)(&lBa[g][n][0]) = f;
        } else if (tid < 260) {
            bf16x8 z = {};
            *(bf16x8*)(&lBa[tid - 256][64][0]) = z;
        }
    }
    __syncthreads();   // the only barrier; waves run independently below

    const int l   = tid & 63;
    const int wv  = tid >> 6;
    const int l15 = l & 15;
    const int lg  = l >> 4;

    const char* lWb = (const char*)(&lWT[0][0][0]);
    const char* lBb = (const char*)(&lBa[0][0][0]);
    char*       lRw = (char*)(&lR[wv][0][0]);

    // tile-invariant offsets
    int baOff[4];
    #pragma unroll
    for (int nt = 0; nt < 4; ++nt)
        baOff[nt] = ((lg == 0) ? (l15 + (nt << 4)) : 64) << 4;
    int wOff[2][4];
    #pragma unroll
    for (int ks = 0; ks < 2; ++ks)
        #pragma unroll
        for (int nt = 0; nt < 4; ++nt) {
            int n = l15 + (nt << 4);
            wOff[ks][nt] = ((n << 7) + (ks << 6) + (lg << 4)) ^ ((n & 7) << 4);
        }
    int rdOff[2];
    #pragma unroll
    for (int ks = 0; ks < 2; ++ks)
        rdOff[ks] = ((l15 << 7) + (ks << 6) + (lg << 4)) ^ ((l15 & 7) << 4);

    const int gw = blockIdx.x * WPB + wv;   // global wave id (< TOTW <= NWT)
    const short one_bf = (short)0x3F80;

    // ---- prologue prefetch (depth 1) ----
    float4 p0, p1, p2, p3;
    float  px0 = 0.f, px1 = 0.f, px2 = 0.f;
    {
        const float* Sr = S + (size_t)((gw << 4) + l15) * 64 + (lg << 3);
        p0 = *(const float4*)(Sr);      p1 = *(const float4*)(Sr + 4);
        p2 = *(const float4*)(Sr + 32); p3 = *(const float4*)(Sr + 36);
        if (lg == 0) {
            const float* Xr = X + (size_t)((gw << 4) + l15) * 3;
            px0 = Xr[0]; px1 = Xr[1]; px2 = Xr[2];
        }
    }

    for (int wt = gw; wt < NWT; wt += TOTW) {
        const int row0 = wt << 4;

        // ---- 1. stage S tile to wave-private LDS (f32, A-layout rows, stride 68) ----
        float* lSr = &lS[wv][l15][0];
        *(float4*)(lSr + (lg << 3))      = p0;
        *(float4*)(lSr + (lg << 3) + 4)  = p1;
        *(float4*)(lSr + (lg << 3) + 32) = p2;
        *(float4*)(lSr + (lg << 3) + 36) = p3;

        // ---- 2. build bf16 fragments from the same registers ----
        bf16x8 aS0, aS1, aX = {};
        aS0[0] = f2b(p0.x); aS0[1] = f2b(p0.y); aS0[2] = f2b(p0.z); aS0[3] = f2b(p0.w);
        aS0[4] = f2b(p1.x); aS0[5] = f2b(p1.y); aS0[6] = f2b(p1.z); aS0[7] = f2b(p1.w);
        aS1[0] = f2b(p2.x); aS1[1] = f2b(p2.y); aS1[2] = f2b(p2.z); aS1[3] = f2b(p2.w);
        aS1[4] = f2b(p3.x); aS1[5] = f2b(p3.y); aS1[6] = f2b(p3.z); aS1[7] = f2b(p3.w);
        aX[0] = f2b(px0); aX[1] = f2b(px1); aX[2] = f2b(px2);
        aX[3] = (lg == 0) ? one_bf : (short)0;

        // ---- 3. issue next tile's loads (latency hides under gates) ----
        int tn = wt + TOTW;
        if (tn < NWT) {
            const float* Sr = S + (size_t)((tn << 4) + l15) * 64 + (lg << 3);
            p0 = *(const float4*)(Sr);      p1 = *(const float4*)(Sr + 4);
            p2 = *(const float4*)(Sr + 32); p3 = *(const float4*)(Sr + 36);
            if (lg == 0) {
                const float* Xr = X + (size_t)((tn << 4) + l15) * 3;
                px0 = Xr[0]; px1 = Xr[1]; px2 = Xr[2];
            }
        }

        // ---- 4. fence lS writes, then issue C-layout sv reads (consumed at Z-epi) ----
        asm volatile("s_waitcnt lgkmcnt(0)" ::: "memory");
        float sv[4][4];
        #pragma unroll
        for (int m = 0; m < 4; ++m)
            #pragma unroll
            for (int nt = 0; nt < 4; ++nt)
                sv[m][nt] = lS[wv][(lg << 2) + m][l15 + (nt << 4)];

        f32x4 acc[4];

        // ---- gate R: write r (bf16, C-layout swizzled) into wave-private lR ----
        gate_mm(lWb + (2 << 13), lBb + 2 * 1040, baOff, wOff, aX, aS0, aS1, acc);
        #pragma unroll
        for (int nt = 0; nt < 4; ++nt) {
            int n = l15 + (nt << 4);
            #pragma unroll
            for (int m = 0; m < 4; ++m) {
                float t  = tanh_fast(acc[nt][m]);
                int rowm = (lg << 2) + m;
                int byt  = ((rowm << 7) + (n << 1)) ^ ((rowm & 7) << 4);
                *(unsigned short*)(lRw + byt) = (unsigned short)f2b(t);
            }
        }

        // ---- gate Z: zs = tanh * sv (sv dies) ----
        float zs[4][4];
        gate_mm(lWb, lBb, baOff, wOff, aX, aS0, aS1, acc);
        #pragma unroll
        for (int nt = 0; nt < 4; ++nt)
            #pragma unroll
            for (int m = 0; m < 4; ++m)
                zs[nt][m] = tanh_fast(acc[nt][m]) * sv[m][nt];

        // ---- gate G ----
        float gq[4][4];
        gate_mm(lWb + (1 << 13), lBb + 1040, baOff, wOff, aX, aS0, aS1, acc);
        #pragma unroll
        for (int nt = 0; nt < 4; ++nt)
            #pragma unroll
            for (int m = 0; m < 4; ++m)
                gq[nt][m] = 1.0f - tanh_fast(acc[nt][m]);

        // ---- gate H: read r back in A-layout, S*R from registers ----
        asm volatile("s_waitcnt lgkmcnt(0)" ::: "memory");
        bf16x8 aR0 = *(const bf16x8*)(lRw + rdOff[0]);
        bf16x8 aR1 = *(const bf16x8*)(lRw + rdOff[1]);
        bf16x8 aH0, aH1;
        #pragma unroll
        for (int i = 0; i < 8; ++i) {
            aH0[i] = f2b(b2f(aS0[i]) * b2f(aR0[i]));
            aH1[i] = f2b(b2f(aS1[i]) * b2f(aR1[i]));
        }
        gate_mm(lWb + (3 << 13), lBb + 3 * 1040, baOff, wOff, aX, aH0, aH1, acc);

        // ---- epilogue: combine + store ----
        float* Or = Out + (size_t)(row0 + (lg << 2)) * 64 + l15;
        #pragma unroll
        for (int nt = 0; nt < 4; ++nt) {
            #pragma unroll
            for (int m = 0; m < 4; ++m) {
                float h = tanh_fast(acc[nt][m]);
                Or[m * 64 + (nt << 4)] = fmaf(gq[nt][m], h, zs[nt][m]);
            }
        }
    }
}

extern "C" void kernel_launch(void* const* d_in, const int* in_sizes, int n_in,
                              void* d_out, int out_size, void* d_ws, size_t ws_size,
                              hipStream_t stream) {
    dim3 grid(GRID), block(384);
    dgm_lstm_kernel<<<grid, block, 0, stream>>>(
        (const float*)d_in[0],  (const float*)d_in[1],
        (const float*)d_in[2],  (const float*)d_in[3],
        (const float*)d_in[4],  (const float*)d_in[5],
        (const float*)d_in[6],  (const float*)d_in[7],
        (const float*)d_in[8],  (const float*)d_in[9],
        (const float*)d_in[10], (const float*)d_in[11],
        (const float*)d_in[12], (const float*)d_in[13],
        (float*)d_out);
}

// Round 8
// 121.399 us; speedup vs baseline: 1.2159x; 1.2159x over previous
//
#include <hip/hip_runtime.h>

#define NWT   62500          // 1,000,000 rows / 16 rows per wave-tile
#define GRID  512
#define WPB   4              // waves per block (256 threads)
#define TOTW  (GRID * WPB)   // 2048 waves

typedef __attribute__((ext_vector_type(8))) short bf16x8;
typedef __attribute__((ext_vector_type(4))) float f32x4;

static __device__ __forceinline__ short f2b(float f) {
    __bf16 h = (__bf16)f;                 // hardware RNE
    return __builtin_bit_cast(short, h);
}
static __device__ __forceinline__ unsigned pack2(float lo, float hi) {
    return ((unsigned)(unsigned short)f2b(lo)) |
           (((unsigned)(unsigned short)f2b(hi)) << 16);
}
static __device__ __forceinline__ float tanh_fast(float x) {
    float e = __expf(2.0f * x);
    return 1.0f - 2.0f * __builtin_amdgcn_rcpf(e + 1.0f);
}

// Swapped-operand gate: acc = Baug(A) x Xaug(B) + W^T(A) x S(B)
// D row-per-lane: lane l15 = batch row, acc[nt][j] = col nt*16+lg*4+j
static __device__ __forceinline__ void gate_mm(const bf16x8 (&wR)[2][4],
                                               const char* lBg, const int (&baOff)[4],
                                               bf16x8 aX, bf16x8 a0, bf16x8 a1,
                                               f32x4 (&acc)[4])
{
    #pragma unroll
    for (int nt = 0; nt < 4; ++nt) {
        bf16x8 bx = *(const bf16x8*)(lBg + baOff[nt]);
        f32x4 z4 = {0.f, 0.f, 0.f, 0.f};
        acc[nt] = __builtin_amdgcn_mfma_f32_16x16x32_bf16(bx, aX, z4, 0, 0, 0);
    }
    #pragma unroll
    for (int ks = 0; ks < 2; ++ks) {
        bf16x8 a = ks ? a1 : a0;
        #pragma unroll
        for (int nt = 0; nt < 4; ++nt)
            acc[nt] = __builtin_amdgcn_mfma_f32_16x16x32_bf16(wR[ks][nt], a, acc[nt], 0, 0, 0);
    }
}

__global__ __launch_bounds__(256, 2)
void dgm_lstm_kernel(const float* __restrict__ S, const float* __restrict__ X,
                     const float* __restrict__ U0, const float* __restrict__ U1,
                     const float* __restrict__ U2, const float* __restrict__ U3,
                     const float* __restrict__ W0, const float* __restrict__ W1,
                     const float* __restrict__ W2, const float* __restrict__ W3,
                     const float* __restrict__ b0, const float* __restrict__ b1,
                     const float* __restrict__ b2, const float* __restrict__ b3,
                     float* __restrict__ Out)
{
    // gate order: 0=z, 1=g, 2=r, 3=h
    __shared__ __align__(16) unsigned short lWT[4][64][64]; // 32 KB: W^T bf16 (staging only)
    __shared__ __align__(16) unsigned short lBa[4][65][8];  // 4.1 KB: [U0,U1,U2,b,0..]; row 64 = zeros
    __shared__ __align__(16) float          lS[WPB][16][68];// 17 KB: S tile f32, wave-private, pad->68
    __shared__ __align__(16) unsigned short lR[WPB][16][64];// 8 KB: (S*R) bf16, wave-private

    const int tid = threadIdx.x;

    // ---- one-time staging: W^T bf16 swizzled; Baug table ----
    {
        const float* Ws[4] = {W0, W1, W2, W3};
        #pragma unroll
        for (int g = 0; g < 4; ++g) {
            #pragma unroll
            for (int it = 0; it < 8; ++it) {
                int p  = it * 256 + tid;            // 0..2047
                int n  = p & 63;
                int k2 = (p >> 6) << 1;
                float w0 = Ws[g][k2 * 64 + n];
                float w1 = Ws[g][k2 * 64 + 64 + n];
                int byt = ((n << 7) + (k2 << 1)) ^ ((n & 7) << 4);
                *(unsigned*)((char*)(&lWT[0][0][0]) + (g << 13) + byt) = pack2(w0, w1);
            }
        }
        const float* Us[4] = {U0, U1, U2, U3};
        const float* bs[4] = {b0, b1, b2, b3};
        int g = tid >> 6, n = tid & 63;
        bf16x8 f = {};
        f[0] = f2b(Us[g][n]);       f[1] = f2b(Us[g][64 + n]);
        f[2] = f2b(Us[g][128 + n]); f[3] = f2b(bs[g][n]);
        *(bf16x8*)(&lBa[g][n][0]) = f;
        if (tid < 4) { bf16x8 z = {}; *(bf16x8*)(&lBa[tid][64][0]) = z; }
    }
    __syncthreads();   // the only barrier; waves run independently below

    const int l   = tid & 63;
    const int wv  = tid >> 6;
    const int l15 = l & 15;
    const int lg  = l >> 4;

    const char* lWb = (const char*)(&lWT[0][0][0]);
    const char* lBb = (const char*)(&lBa[0][0][0]);
    char*       lRw = (char*)(&lR[wv][0][0]);

    // ---- load ALL weight A-fragments into registers (loop-invariant) ----
    bf16x8 wReg[4][2][4];
    #pragma unroll
    for (int g = 0; g < 4; ++g)
        #pragma unroll
        for (int ks = 0; ks < 2; ++ks)
            #pragma unroll
            for (int nt = 0; nt < 4; ++nt) {
                int n = l15 + (nt << 4);
                int byt = ((n << 7) + (ks << 6) + (lg << 4)) ^ ((n & 7) << 4);
                wReg[g][ks][nt] = *(const bf16x8*)(lWb + (g << 13) + byt);
            }

    // tile-invariant offsets
    int baOff[4];
    #pragma unroll
    for (int nt = 0; nt < 4; ++nt)
        baOff[nt] = ((lg == 0) ? (l15 + (nt << 4)) : 64) << 4;
    // lR: row-major [16][64] bf16, XOR-swizzled by row
    int wrOff[4];                         // write: row l15, cols nt*16+lg*4 (b64)
    #pragma unroll
    for (int nt = 0; nt < 4; ++nt)
        wrOff[nt] = ((l15 << 7) + (nt << 5) + (lg << 3)) ^ ((l15 & 7) << 4);
    int rdOff[2];                         // read: row l15, cols ks*32+lg*8 (b128)
    #pragma unroll
    for (int ks = 0; ks < 2; ++ks)
        rdOff[ks] = ((l15 << 7) + (ks << 6) + (lg << 4)) ^ ((l15 & 7) << 4);

    const int gw = blockIdx.x * WPB + wv;   // global wave id
    const short one_bf = (short)0x3F80;

    // ---- prologue prefetch (depth 1) ----
    float4 p0, p1, p2, p3;
    float  px0 = 0.f, px1 = 0.f, px2 = 0.f;
    {
        const float* Sr = S + (size_t)((gw << 4) + l15) * 64 + (lg << 3);
        p0 = *(const float4*)(Sr);      p1 = *(const float4*)(Sr + 4);
        p2 = *(const float4*)(Sr + 32); p3 = *(const float4*)(Sr + 36);
        if (lg == 0) {
            const float* Xr = X + (size_t)((gw << 4) + l15) * 3;
            px0 = Xr[0]; px1 = Xr[1]; px2 = Xr[2];
        }
    }

    for (int wt = gw; wt < NWT; wt += TOTW) {
        const int row0 = wt << 4;

        // ---- 1. stage S tile to wave-private LDS (f32, row l15, stride 68) ----
        float* lSr = &lS[wv][l15][0];
        *(float4*)(lSr + (lg << 3))      = p0;
        *(float4*)(lSr + (lg << 3) + 4)  = p1;
        *(float4*)(lSr + (lg << 3) + 32) = p2;
        *(float4*)(lSr + (lg << 3) + 36) = p3;

        // ---- 2. build bf16 B-fragments from the same registers ----
        bf16x8 aS0, aS1, aX = {};
        aS0[0] = f2b(p0.x); aS0[1] = f2b(p0.y); aS0[2] = f2b(p0.z); aS0[3] = f2b(p0.w);
        aS0[4] = f2b(p1.x); aS0[5] = f2b(p1.y); aS0[6] = f2b(p1.z); aS0[7] = f2b(p1.w);
        aS1[0] = f2b(p2.x); aS1[1] = f2b(p2.y); aS1[2] = f2b(p2.z); aS1[3] = f2b(p2.w);
        aS1[4] = f2b(p3.x); aS1[5] = f2b(p3.y); aS1[6] = f2b(p3.z); aS1[7] = f2b(p3.w);
        aX[0] = f2b(px0); aX[1] = f2b(px1); aX[2] = f2b(px2);
        aX[3] = (lg == 0) ? one_bf : (short)0;

        // ---- 3. issue next tile's loads (latency hides under gates) ----
        int tn = wt + TOTW;
        if (tn < NWT) {
            const float* Sr = S + (size_t)((tn << 4) + l15) * 64 + (lg << 3);
            p0 = *(const float4*)(Sr);      p1 = *(const float4*)(Sr + 4);
            p2 = *(const float4*)(Sr + 32); p3 = *(const float4*)(Sr + 36);
            if (lg == 0) {
                const float* Xr = X + (size_t)((tn << 4) + l15) * 3;
                px0 = Xr[0]; px1 = Xr[1]; px2 = Xr[2];
            }
        }

        // ---- 4. fence lS writes; sv = S[l15][nt*16+lg*4 .. +4] (row-per-lane) ----
        asm volatile("s_waitcnt lgkmcnt(0)" ::: "memory");
        f32x4 sv[4];
        #pragma unroll
        for (int nt = 0; nt < 4; ++nt)
            sv[nt] = *(const f32x4*)(&lS[wv][l15][(nt << 4) + (lg << 2)]);

        f32x4 acc[4];

        // ---- gate R: sr = sv * tanh(acc) in f32; write bf16 pairs (b64) ----
        gate_mm(wReg[2], lBb + 2 * 1040, baOff, aX, aS0, aS1, acc);
        #pragma unroll
        for (int nt = 0; nt < 4; ++nt) {
            float sr0 = sv[nt][0] * tanh_fast(acc[nt][0]);
            float sr1 = sv[nt][1] * tanh_fast(acc[nt][1]);
            float sr2 = sv[nt][2] * tanh_fast(acc[nt][2]);
            float sr3 = sv[nt][3] * tanh_fast(acc[nt][3]);
            uint2 w;
            w.x = pack2(sr0, sr1);
            w.y = pack2(sr2, sr3);
            *(uint2*)(lRw + wrOff[nt]) = w;
        }

        // ---- gate Z: zs = tanh * sv ----
        f32x4 zs;
        float zsv[4][4];
        gate_mm(wReg[0], lBb, baOff, aX, aS0, aS1, acc);
        #pragma unroll
        for (int nt = 0; nt < 4; ++nt)
            #pragma unroll
            for (int j = 0; j < 4; ++j)
                zsv[nt][j] = tanh_fast(acc[nt][j]) * sv[nt][j];
        (void)zs;

        // ---- gate G: gq = 1 - tanh ----
        float gq[4][4];
        gate_mm(wReg[1], lBb + 1040, baOff, aX, aS0, aS1, acc);
        #pragma unroll
        for (int nt = 0; nt < 4; ++nt)
            #pragma unroll
            for (int j = 0; j < 4; ++j)
                gq[nt][j] = 1.0f - tanh_fast(acc[nt][j]);

        // ---- gate H: read (S*R) back as B-fragment (row l15, k-contiguous) ----
        asm volatile("s_waitcnt lgkmcnt(0)" ::: "memory");
        bf16x8 aR0 = *(const bf16x8*)(lRw + rdOff[0]);
        bf16x8 aR1 = *(const bf16x8*)(lRw + rdOff[1]);
        gate_mm(wReg[3], lBb + 3 * 1040, baOff, aX, aR0, aR1, acc);

        // ---- epilogue: combine + coalesced dwordx4 stores ----
        float* Or = Out + (size_t)(row0 + l15) * 64 + (lg << 2);
        #pragma unroll
        for (int nt = 0; nt < 4; ++nt) {
            float4 o;
            o.x = fmaf(gq[nt][0], tanh_fast(acc[nt][0]), zsv[nt][0]);
            o.y = fmaf(gq[nt][1], tanh_fast(acc[nt][1]), zsv[nt][1]);
            o.z = fmaf(gq[nt][2], tanh_fast(acc[nt][2]), zsv[nt][2]);
            o.w = fmaf(gq[nt][3], tanh_fast(acc[nt][3]), zsv[nt][3]);
            *(float4*)(Or + (nt << 4)) = o;
        }
    }
}

extern "C" void kernel_launch(void* const* d_in, const int* in_sizes, int n_in,
                              void* d_out, int out_size, void* d_ws, size_t ws_size,
                              hipStream_t stream) {
    dim3 grid(GRID), block(256);
    dgm_lstm_kernel<<<grid, block, 0, stream>>>(
        (const float*)d_in[0],  (const float*)d_in[1],
        (const float*)d_in[2],  (const float*)d_in[3],
        (const float*)d_in[4],  (const float*)d_in[5],
        (const float*)d_in[6],  (const float*)d_in[7],
        (const float*)d_in[8],  (const float*)d_in[9],
        (const float*)d_in[10], (const float*)d_in[11],
        (const float*)d_in[12], (const float*)d_in[13],
        (float*)d_out);
}